// Round 7
// baseline (448.626 us; speedup 1.0000x reference)
//
#include <hip/hip_runtime.h>
#include <hip/hip_bf16.h>
#include <stdint.h>
#include <math.h>

#define DIMC 2048
#define NH 16
#define HD 128
#define BBATCH 2
#define TSEQ 2048
#define MROWS (BBATCH*TSEQ)   // 4096
#define NQKV (3*DIMC)         // 6144

typedef __attribute__((ext_vector_type(8))) short short8;
typedef __attribute__((ext_vector_type(4))) float f32x4;

#define BAR() asm volatile("s_barrier" ::: "memory")

__device__ __forceinline__ short f2bf(float f) {
  union { float f; uint32_t u; } v; v.f = f;
  uint32_t r = (v.u + 0x7fffu + ((v.u >> 16) & 1u)) >> 16;
  return (short)(uint16_t)r;
}
__device__ __forceinline__ float bf2f(short s) {
  union { uint32_t u; float f; } v; v.u = ((uint32_t)(uint16_t)s) << 16;
  return v.f;
}
__device__ __forceinline__ void g2lds16(const void* g, void* l) {
  __builtin_amdgcn_global_load_lds((const __attribute__((address_space(1))) void*)g,
                                   (__attribute__((address_space(3))) void*)l, 16, 0, 0);
}

// ---------------- RoPE tables: cos/sin [T][64] ----------------
__global__ void rope_tables(float* __restrict__ cos_t, float* __restrict__ sin_t) {
  int idx = blockIdx.x * blockDim.x + threadIdx.x;   // T*64
  int t = idx >> 6, j = idx & 63;
  double inv = exp(-((double)(2 * j) / 128.0) * log(10000.0));
  float fr = (float)t * (float)inv;
  cos_t[idx] = cosf(fr);
  sin_t[idx] = sinf(fr);
}

// ---------------- fp32 -> bf16 cast (8 elems/thread) ----------------
__global__ void cast_f32_bf16(const float* __restrict__ in, short* __restrict__ out, int n8) {
  int i = blockIdx.x * blockDim.x + threadIdx.x;
  if (i >= n8) return;
  const float4* p = (const float4*)in;
  float4 a = p[2 * i], b = p[2 * i + 1];
  short8 o;
  o[0] = f2bf(a.x); o[1] = f2bf(a.y); o[2] = f2bf(a.z); o[3] = f2bf(a.w);
  o[4] = f2bf(b.x); o[5] = f2bf(b.y); o[6] = f2bf(b.z); o[7] = f2bf(b.w);
  ((short8*)out)[i] = o;
}

// ---------------- in-place RoPE on q,k [B,H,T,HD] bf16 ----------------
__global__ void rope_apply(short* __restrict__ q, short* __restrict__ k,
                           const float* __restrict__ cos_t, const float* __restrict__ sin_t) {
  int idx = blockIdx.x * blockDim.x + threadIdx.x;  // B*H*T*64
  int j = idx & 63;
  int t = (idx >> 6) & (TSEQ - 1);
  int bh = idx >> 17;
  size_t base = ((size_t)bh * TSEQ + t) * HD;
  float c = cos_t[t * 64 + j], s = sin_t[t * 64 + j];
  float x1 = bf2f(q[base + j]), x2 = bf2f(q[base + j + 64]);
  q[base + j]      = f2bf(x1 * c - x2 * s);
  q[base + j + 64] = f2bf(x2 * c + x1 * s);
  float y1 = bf2f(k[base + j]), y2 = bf2f(k[base + j + 64]);
  k[base + j]      = f2bf(y1 * c - y2 * s);
  k[base + j + 64] = f2bf(y2 * c + y1 * s);
}

// ======================= 256x256 8-phase GEMM (m201 port) =======================
// C = A(bf16 MxK) * B(bf16 NxK)^T.  BM=BN=256, BK=64, 512 thr = 8 waves (2M x 4N),
// per-wave C = 128x64.  LDS: half-tile slabs A[2][2],B[2][2] (128x64 each) = 128KB.
// 8 phases / 2 K-tiles; each phase: {ds_reads; stage 1 half-tile; [vmcnt(4) @p3/p7];
// BAR; setprio1; 16 MFMA; setprio0; BAR}.  Staging stream gives every half-tile a
// >=3-phase landing lead; vmcnt is never 0 except the final iteration.
// LDS swizzle: phys chunk = c ^ (row&7) (16B granule), involution on both sides.
__device__ __forceinline__ void stage128(short* lds_base, const short* gsrc, int ldg, int tid) {
  #pragma unroll
  for (int j = 0; j < 2; ++j) {
    int L = j * 512 + tid;            // 16B chunk 0..1023 of a 128x64 slab
    int r = L >> 3, pc = L & 7;
    g2lds16(gsrc + (size_t)r * ldg + ((pc ^ (r & 7)) << 3), lds_base + L * 8);
  }
}
__device__ __forceinline__ short8 ldsfrag(const short* base, int row, int c) {
  return *(const short8*)(base + row * 64 + ((c ^ (row & 7)) << 3));
}

template<int Q>
__device__ __forceinline__ void mfma16(short8 (&afr)[8][2], short8 (&bfr)[4][2],
                                       f32x4 (&acc)[8][4]) {
  constexpr int rh = Q >> 1, ch = Q & 1;
  #pragma unroll
  for (int m2 = 0; m2 < 4; ++m2)
    #pragma unroll
    for (int n2 = 0; n2 < 2; ++n2)
      #pragma unroll
      for (int ks = 0; ks < 2; ++ks)
        acc[rh * 4 + m2][ch * 2 + n2] = __builtin_amdgcn_mfma_f32_16x16x32_bf16(
            afr[rh * 4 + m2][ks], bfr[ch * 2 + n2][ks], acc[rh * 4 + m2][ch * 2 + n2], 0, 0, 0);
}
template<int H>
__device__ __forceinline__ void loads_half(short8 (&afr)[8][2], short8 (&bfr)[4][2],
                                           const short* Acur, const short* Bcur,
                                           int brow, int l15, int l4) {
  #pragma unroll
  for (int m2 = 0; m2 < 4; ++m2)
    #pragma unroll
    for (int ks = 0; ks < 2; ++ks)
      afr[H * 4 + m2][ks] = ldsfrag(Acur, H * 64 + m2 * 16 + l15, ks * 4 + l4);
  #pragma unroll
  for (int n2 = 0; n2 < 2; ++n2)
    #pragma unroll
    for (int ks = 0; ks < 2; ++ks)
      bfr[H * 2 + n2][ks] = ldsfrag(Bcur, brow + H * 32 + n2 * 16 + l15, ks * 4 + l4);
}

template<int EPI>
__global__ __launch_bounds__(512, 2)
void gemm256(const short* __restrict__ A, const short* __restrict__ B,
             int M, int N, int K,
             float* __restrict__ Cout,
             short* __restrict__ qp, short* __restrict__ kp, short* __restrict__ vp) {
  __shared__ short Asl[2][2][128 * 64];   // [K-tile parity][half] 64 KB
  __shared__ short Bsl[2][2][128 * 64];   // 64 KB
  const int tid = threadIdx.x, lane = tid & 63, wave = tid >> 6;
  const int wm = wave >> 2, wn = wave & 3;
  const int l15 = lane & 15, l4 = lane >> 4;
  // chunked bijective XCD swizzle (both grids have nwg % 8 == 0)
  const int nwg = gridDim.x * gridDim.y;
  const int orig = blockIdx.y * gridDim.x + blockIdx.x;
  const int wg = (orig & 7) * (nwg >> 3) + (orig >> 3);
  const int bn = wg % gridDim.x, bm = wg / gridDim.x;
  const int rowA0 = bm * 256, rowB0 = bn * 256;
  const int NT = K / 64;                  // even, >= 6 (here 32)
  f32x4 acc[8][4] = {};
  short8 afr[8][2], bfr[4][2];

  auto stA = [&](int kt, int h) {
    if (kt < NT) stage128(&Asl[kt & 1][h][0], A + (size_t)(rowA0 + h * 128) * K + kt * 64, K, tid);
  };
  auto stB = [&](int kt, int h) {
    if (kt < NT) stage128(&Bsl[kt & 1][h][0], B + (size_t)(rowB0 + h * 128) * K + kt * 64, K, tid);
  };

  // prologue: A(0)h0,h1  B(0)h0,h1  A(1)h0,h1 ; wait all but A(1) (4 loads) in flight
  stA(0, 0); stA(0, 1); stB(0, 0); stB(0, 1); stA(1, 0); stA(1, 1);
  asm volatile("s_waitcnt vmcnt(4)" ::: "memory");
  BAR();

  const short* A0 = &Asl[0][wm][0];
  const short* B0 = &Bsl[0][wn >> 1][0];
  const short* A1 = &Asl[1][wm][0];
  const short* B1 = &Bsl[1][wn >> 1][0];
  const int brow = (wn & 1) * 64;

  for (int t = 0; t < NT / 2; ++t) {
    const int k0 = 2 * t, k1 = 2 * t + 1;
    const bool lastIt = (t == NT / 2 - 1);
    // ---- phase 0 (K-tile k0, quadrant 0) ----
    loads_half<0>(afr, bfr, A0, B0, brow, l15, l4);
    stB(k1, 0);
    BAR();
    __builtin_amdgcn_s_setprio(1); mfma16<0>(afr, bfr, acc); __builtin_amdgcn_s_setprio(0);
    BAR();
    // ---- phase 1 (q1) ----
    loads_half<1>(afr, bfr, A0, B0, brow, l15, l4);
    stB(k1, 1);
    BAR();
    __builtin_amdgcn_s_setprio(1); mfma16<1>(afr, bfr, acc); __builtin_amdgcn_s_setprio(0);
    BAR();
    // ---- phase 2 (q2) ----
    stA(k0 + 2, 0);
    BAR();
    __builtin_amdgcn_s_setprio(1); mfma16<2>(afr, bfr, acc); __builtin_amdgcn_s_setprio(0);
    BAR();
    // ---- phase 3 (q3) + counted wait ----
    stA(k0 + 2, 1);
    if (lastIt) asm volatile("s_waitcnt vmcnt(0)" ::: "memory");
    else        asm volatile("s_waitcnt vmcnt(4)" ::: "memory");
    BAR();
    __builtin_amdgcn_s_setprio(1); mfma16<3>(afr, bfr, acc); __builtin_amdgcn_s_setprio(0);
    BAR();
    // ---- phase 4 (K-tile k1, quadrant 0) ----
    loads_half<0>(afr, bfr, A1, B1, brow, l15, l4);
    stB(k0 + 2, 0);
    BAR();
    __builtin_amdgcn_s_setprio(1); mfma16<0>(afr, bfr, acc); __builtin_amdgcn_s_setprio(0);
    BAR();
    // ---- phase 5 (q1) ----
    loads_half<1>(afr, bfr, A1, B1, brow, l15, l4);
    stB(k0 + 2, 1);
    BAR();
    __builtin_amdgcn_s_setprio(1); mfma16<1>(afr, bfr, acc); __builtin_amdgcn_s_setprio(0);
    BAR();
    // ---- phase 6 (q2) ----
    stA(k1 + 2, 0);
    BAR();
    __builtin_amdgcn_s_setprio(1); mfma16<2>(afr, bfr, acc); __builtin_amdgcn_s_setprio(0);
    BAR();
    // ---- phase 7 (q3) + counted wait ----
    stA(k1 + 2, 1);
    if (!lastIt) asm volatile("s_waitcnt vmcnt(4)" ::: "memory");
    BAR();
    __builtin_amdgcn_s_setprio(1); mfma16<3>(afr, bfr, acc); __builtin_amdgcn_s_setprio(0);
    BAR();
  }

  // epilogue: frag m covers wave-rows (m>>2)*64+(m&3)*16; frag n covers cols (n>>1)*32+(n&1)*16
  if (EPI == 1) {
    #pragma unroll
    for (int m = 0; m < 8; ++m)
      #pragma unroll
      for (int n = 0; n < 4; ++n)
        #pragma unroll
        for (int i = 0; i < 4; ++i) {
          int gm = rowA0 + wm * 128 + (m >> 2) * 64 + (m & 3) * 16 + (l4 << 2) + i;
          int gn = rowB0 + wn * 64 + (n >> 1) * 32 + (n & 1) * 16 + l15;
          Cout[(size_t)gm * N + gn] = acc[m][n][i];
        }
  } else {
    short* dst = (bn < 8) ? qp : (bn < 16) ? kp : vp;
    #pragma unroll
    for (int m = 0; m < 8; ++m)
      #pragma unroll
      for (int n = 0; n < 4; ++n)
        #pragma unroll
        for (int i = 0; i < 4; ++i) {
          int gm = rowA0 + wm * 128 + (m >> 2) * 64 + (m & 3) * 16 + (l4 << 2) + i;
          int c  = rowB0 + wn * 64 + (n >> 1) * 32 + (n & 1) * 16 + l15;
          int b = gm >> 11, tt = gm & 2047;
          int h = (c >> 7) & 15, d = c & 127;
          dst[(((size_t)b * NH + h) * TSEQ + tt) * HD + d] = f2bf(acc[m][n][i]);
        }
  }
}

// ---------------- flash attention (causal), QBLK=64, KVBLK=64 ----------------
// LDS swizzles (all bijective chunk-XOR within rows; rule #21 both-sides):
//  Ks : phys(row,k)  = row*128 + ((k>>3 ^ (row&7))<<3) + (k&7)     [staged via pre-swizzled g2lds src]
//  Vt : phys(d,kv)   = d*64 + ((kv>>3 ^ (d&7) ^ ((d>>3)&7))<<3) + (kv&7)
//  Pl : phys(q,kv)   = q*64 + ((kv>>3 ^ (q&7))<<3) + (kv&7)
__global__ __launch_bounds__(256)
void flash_attn(const short* __restrict__ Q, const short* __restrict__ K,
                const short* __restrict__ V, short* __restrict__ Oout) {
  __shared__ short Ks[64 * 128];     // 16KB
  __shared__ short Vt[128 * 64];     // 16KB transposed V, swizzled
  __shared__ short Pl[4 * 16 * 64];  // 8KB per-wave P, swizzled
  int tid = threadIdx.x, lane = tid & 63, wave = tid >> 6;
  // heavy-first dispatch: qt descending across bid; same (b,h) sticks to one XCD
  int bid = blockIdx.x;
  int qt = (TSEQ / 64 - 1) - (bid >> 5);
  int hb = bid & 31;
  int h = hb & 15, b = hb >> 4;
  size_t bh_off = ((size_t)b * NH + h) * TSEQ * HD;
  const short* Qp = Q + bh_off;
  const short* Kp = K + bh_off;
  const short* Vp = V + bh_off;
  int q0 = qt * 64 + wave * 16;
  short8 qf[4];
  #pragma unroll
  for (int ks = 0; ks < 4; ++ks)
    qf[ks] = *(const short8*)(Qp + (size_t)(q0 + (lane & 15)) * HD + ks * 32 + 8 * (lane >> 4));
  float m_run[4], l_run[4];
  f32x4 acc_o[8] = {};
  #pragma unroll
  for (int i = 0; i < 4; ++i) { m_run[i] = -INFINITY; l_run[i] = 0.f; }
  const float scale = 0.08838834764831845f;  // 1/sqrt(128)
  for (int it = 0; it <= qt; ++it) {
    int kv0 = it * 64;
    // V tile -> regs (issue first; latency hides under K staging)
    short8 vv[4];
    #pragma unroll
    for (int j = 0; j < 4; ++j) {
      int e = tid + j * 256;
      int r = e >> 4, c0 = (e & 15) * 8;
      vv[j] = *(const short8*)(Vp + (size_t)(kv0 + r) * HD + c0);
    }
    // stage K (64x128), pre-swizzled source chunk so swizzled read is linear-dest-safe
    #pragma unroll
    for (int j = 0; j < 4; ++j) {
      int c = tid + j * 256;          // physical 16B chunk index
      int r = c >> 4, cc = c & 15;
      g2lds16(Kp + (size_t)(kv0 + r) * HD + ((cc ^ (r & 7)) << 3), Ks + c * 8);
    }
    // scatter V transpose into swizzled Vt
    #pragma unroll
    for (int j = 0; j < 4; ++j) {
      int e = tid + j * 256;
      int r = e >> 4, c0 = (e & 15) * 8;
      int rc = r >> 3, rl = r & 7;
      #pragma unroll
      for (int jj = 0; jj < 8; ++jj) {
        int d = c0 + jj;
        int pch = rc ^ (d & 7) ^ ((d >> 3) & 7);
        Vt[d * 64 + (pch << 3) + rl] = vv[j][jj];
      }
    }
    __syncthreads();
    // S = Q K^T  (16 q-rows x 64 kv)
    f32x4 sa[4] = {};
    __builtin_amdgcn_s_setprio(1);
    #pragma unroll
    for (int nf = 0; nf < 4; ++nf)
      #pragma unroll
      for (int ks = 0; ks < 4; ++ks) {
        int row = nf * 16 + (lane & 15);
        int lch = ks * 4 + (lane >> 4);
        short8 kf = *(const short8*)(Ks + row * 128 + ((lch ^ (row & 7)) << 3));
        sa[nf] = __builtin_amdgcn_mfma_f32_16x16x32_bf16(qf[ks], kf, sa[nf], 0, 0, 0);
      }
    __builtin_amdgcn_s_setprio(0);
    bool lastTile = (it == qt);
    #pragma unroll
    for (int nf = 0; nf < 4; ++nf)
      #pragma unroll
      for (int i = 0; i < 4; ++i) {
        float s = sa[nf][i] * scale;
        if (lastTile) {
          int kvc = kv0 + nf * 16 + (lane & 15);
          int qr = q0 + ((lane >> 4) << 2) + i;
          if (kvc > qr) s = -INFINITY;
        }
        sa[nf][i] = s;
      }
    // online softmax per q-row (rows live across 16 lanes)
    #pragma unroll
    for (int i = 0; i < 4; ++i) {
      float t = fmaxf(fmaxf(sa[0][i], sa[1][i]), fmaxf(sa[2][i], sa[3][i]));
      t = fmaxf(t, __shfl_xor(t, 1));
      t = fmaxf(t, __shfl_xor(t, 2));
      t = fmaxf(t, __shfl_xor(t, 4));
      t = fmaxf(t, __shfl_xor(t, 8));
      float mn = fmaxf(m_run[i], t);
      float al = __expf(m_run[i] - mn);
      m_run[i] = mn;
      float su = 0.f;
      #pragma unroll
      for (int nf = 0; nf < 4; ++nf) {
        float p = __expf(sa[nf][i] - mn);
        sa[nf][i] = p;
        su += p;
      }
      su += __shfl_xor(su, 1);
      su += __shfl_xor(su, 2);
      su += __shfl_xor(su, 4);
      su += __shfl_xor(su, 8);
      l_run[i] = l_run[i] * al + su;
      #pragma unroll
      for (int nfd = 0; nfd < 8; ++nfd) acc_o[nfd][i] *= al;
    }
    // P -> LDS (per wave, swizzled)
    short* Pw = Pl + wave * 16 * 64;
    #pragma unroll
    for (int nf = 0; nf < 4; ++nf)
      #pragma unroll
      for (int i = 0; i < 4; ++i) {
        int qq = ((lane >> 4) << 2) + i;
        int kv = nf * 16 + (lane & 15);
        Pw[qq * 64 + (((kv >> 3) ^ (qq & 7)) << 3) + (kv & 7)] = f2bf(sa[nf][i]);
      }
    // O += P V
    __builtin_amdgcn_s_setprio(1);
    #pragma unroll
    for (int ks2 = 0; ks2 < 2; ++ks2) {
      int qq = lane & 15;
      int lchp = ks2 * 4 + (lane >> 4);
      short8 pf = *(const short8*)(Pw + qq * 64 + ((lchp ^ (qq & 7)) << 3));
      #pragma unroll
      for (int nfd = 0; nfd < 8; ++nfd) {
        int d = nfd * 16 + (lane & 15);
        int lch = ks2 * 4 + (lane >> 4);
        int pch = lch ^ (d & 7) ^ ((d >> 3) & 7);
        short8 vf = *(const short8*)(Vt + d * 64 + (pch << 3));
        acc_o[nfd] = __builtin_amdgcn_mfma_f32_16x16x32_bf16(pf, vf, acc_o[nfd], 0, 0, 0);
      }
    }
    __builtin_amdgcn_s_setprio(0);
    __syncthreads();
  }
  // epilogue: O /= l, write bf16 to attn_out [B,T,DIM]
  #pragma unroll
  for (int nfd = 0; nfd < 8; ++nfd)
    #pragma unroll
    for (int i = 0; i < 4; ++i) {
      int qr = q0 + ((lane >> 4) << 2) + i;
      int col = h * HD + nfd * 16 + (lane & 15);
      Oout[((size_t)b * TSEQ + qr) * DIMC + col] = f2bf(acc_o[nfd][i] / l_run[i]);
    }
}

extern "C" void kernel_launch(void* const* d_in, const int* in_sizes, int n_in,
                              void* d_out, int out_size, void* d_ws, size_t ws_size,
                              hipStream_t stream) {
  const float* x     = (const float*)d_in[0];
  const float* w_qkv = (const float*)d_in[1];
  const float* w_out = (const float*)d_in[2];
  float* out = (float*)d_out;
  char* ws = (char*)d_ws;
  size_t off = 0;
  auto alloc = [&](size_t bytes) {
    void* p = ws + off;
    off += (bytes + 255) & ~(size_t)255;
    return p;
  };
  float* cos_t = (float*)alloc((size_t)TSEQ * 64 * 4);
  float* sin_t = (float*)alloc((size_t)TSEQ * 64 * 4);
  short* xb    = (short*)alloc((size_t)MROWS * DIMC * 2);
  short* wqkvb = (short*)alloc((size_t)NQKV * DIMC * 2);
  short* woutb = (short*)alloc((size_t)DIMC * DIMC * 2);
  short* q     = (short*)alloc((size_t)BBATCH * NH * TSEQ * HD * 2);
  short* k     = (short*)alloc((size_t)BBATCH * NH * TSEQ * HD * 2);
  short* v     = (short*)alloc((size_t)BBATCH * NH * TSEQ * HD * 2);
  short* attn  = (short*)alloc((size_t)MROWS * DIMC * 2);

  rope_tables<<<(TSEQ * 64) / 256, 256, 0, stream>>>(cos_t, sin_t);
  cast_f32_bf16<<<(MROWS * DIMC / 8 + 255) / 256, 256, 0, stream>>>(x, xb, MROWS * DIMC / 8);
  cast_f32_bf16<<<(NQKV * DIMC / 8 + 255) / 256, 256, 0, stream>>>(w_qkv, wqkvb, NQKV * DIMC / 8);
  cast_f32_bf16<<<(DIMC * DIMC / 8 + 255) / 256, 256, 0, stream>>>(w_out, woutb, DIMC * DIMC / 8);

  gemm256<0><<<dim3(NQKV / 256, MROWS / 256), 512, 0, stream>>>(
      xb, wqkvb, MROWS, NQKV, DIMC, nullptr, q, k, v);

  rope_apply<<<(BBATCH * NH * TSEQ * 64) / 256, 256, 0, stream>>>(q, k, cos_t, sin_t);

  flash_attn<<<dim3((TSEQ / 64) * NH * BBATCH), 256, 0, stream>>>(q, k, v, attn);

  gemm256<1><<<dim3(DIMC / 256, MROWS / 256), 512, 0, stream>>>(
      attn, woutb, MROWS, DIMC, DIMC, out, nullptr, nullptr, nullptr);
}

// Round 8
// 447.995 us; speedup vs baseline: 1.0014x; 1.0014x over previous
//
#include <hip/hip_runtime.h>
#include <hip/hip_bf16.h>
#include <stdint.h>
#include <math.h>

#define DIMC 2048
#define NH 16
#define HD 128
#define BBATCH 2
#define TSEQ 2048
#define MROWS (BBATCH*TSEQ)   // 4096
#define NQKV (3*DIMC)         // 6144

typedef __attribute__((ext_vector_type(8))) short short8;
typedef __attribute__((ext_vector_type(4))) float f32x4;

__device__ __forceinline__ short f2bf(float f) {
  union { float f; uint32_t u; } v; v.f = f;
  uint32_t r = (v.u + 0x7fffu + ((v.u >> 16) & 1u)) >> 16;
  return (short)(uint16_t)r;
}
__device__ __forceinline__ float bf2f(short s) {
  union { uint32_t u; float f; } v; v.u = ((uint32_t)(uint16_t)s) << 16;
  return v.f;
}
__device__ __forceinline__ void g2lds16(const void* g, void* l) {
  __builtin_amdgcn_global_load_lds((const __attribute__((address_space(1))) void*)g,
                                   (__attribute__((address_space(3))) void*)l, 16, 0, 0);
}

// ---------------- RoPE tables: cos/sin [T][64] ----------------
__global__ void rope_tables(float* __restrict__ cos_t, float* __restrict__ sin_t) {
  int idx = blockIdx.x * blockDim.x + threadIdx.x;   // T*64
  int t = idx >> 6, j = idx & 63;
  double inv = exp(-((double)(2 * j) / 128.0) * log(10000.0));
  float fr = (float)t * (float)inv;
  cos_t[idx] = cosf(fr);
  sin_t[idx] = sinf(fr);
}

// ---------------- fp32 -> bf16 cast (8 elems/thread) ----------------
__global__ void cast_f32_bf16(const float* __restrict__ in, short* __restrict__ out, int n8) {
  int i = blockIdx.x * blockDim.x + threadIdx.x;
  if (i >= n8) return;
  const float4* p = (const float4*)in;
  float4 a = p[2 * i], b = p[2 * i + 1];
  short8 o;
  o[0] = f2bf(a.x); o[1] = f2bf(a.y); o[2] = f2bf(a.z); o[3] = f2bf(a.w);
  o[4] = f2bf(b.x); o[5] = f2bf(b.y); o[6] = f2bf(b.z); o[7] = f2bf(b.w);
  ((short8*)out)[i] = o;
}

// ---------------- in-place RoPE on q,k [B,H,T,HD] bf16 ----------------
__global__ void rope_apply(short* __restrict__ q, short* __restrict__ k,
                           const float* __restrict__ cos_t, const float* __restrict__ sin_t) {
  int idx = blockIdx.x * blockDim.x + threadIdx.x;  // B*H*T*64
  int j = idx & 63;
  int t = (idx >> 6) & (TSEQ - 1);
  int bh = idx >> 17;
  size_t base = ((size_t)bh * TSEQ + t) * HD;
  float c = cos_t[t * 64 + j], s = sin_t[t * 64 + j];
  float x1 = bf2f(q[base + j]), x2 = bf2f(q[base + j + 64]);
  q[base + j]      = f2bf(x1 * c - x2 * s);
  q[base + j + 64] = f2bf(x2 * c + x1 * s);
  float y1 = bf2f(k[base + j]), y2 = bf2f(k[base + j + 64]);
  k[base + j]      = f2bf(y1 * c - y2 * s);
  k[base + j + 64] = f2bf(y2 * c + y1 * s);
}

// ---------------- GEMM C = A(bf16 MxK) * B(bf16 NxK)^T (round-5 verified) ----------------
// EPI 0: scatter to q/k/v bf16 [B,H,T,HD]   EPI 1: fp32 row-major Cout
template<int EPI>
__global__ __launch_bounds__(256)
void gemm_bt(const short* __restrict__ A, const short* __restrict__ B,
             int M, int N, int K,
             float* __restrict__ Cout,
             short* __restrict__ qp, short* __restrict__ kp, short* __restrict__ vp) {
  __shared__ short As[128 * 32];
  __shared__ short Bs[128 * 32];
  int tid = threadIdx.x;
  int lane = tid & 63, wave = tid >> 6;
  int wr = wave >> 1, wc = wave & 1;
  int bm = blockIdx.y, bn = blockIdx.x;
  int rowA0 = bm * 128, rowB0 = bn * 128;
  f32x4 acc[4][4] = {};
  for (int k0 = 0; k0 < K; k0 += 32) {
    #pragma unroll
    for (int j = 0; j < 2; ++j) {
      int c = tid + j * 256;           // 0..511 chunks of 16B
      int r = c >> 2, kk = (c & 3) * 8;
      g2lds16(A + (size_t)(rowA0 + r) * K + k0 + kk, As + c * 8);
      g2lds16(B + (size_t)(rowB0 + r) * K + k0 + kk, Bs + c * 8);
    }
    __syncthreads();
    short8 af[4], bfr[4];
    #pragma unroll
    for (int mf = 0; mf < 4; ++mf)
      af[mf] = *(const short8*)(As + (wr * 64 + mf * 16 + (lane & 15)) * 32 + 8 * (lane >> 4));
    #pragma unroll
    for (int nf = 0; nf < 4; ++nf)
      bfr[nf] = *(const short8*)(Bs + (wc * 64 + nf * 16 + (lane & 15)) * 32 + 8 * (lane >> 4));
    #pragma unroll
    for (int mf = 0; mf < 4; ++mf)
      #pragma unroll
      for (int nf = 0; nf < 4; ++nf)
        acc[mf][nf] = __builtin_amdgcn_mfma_f32_16x16x32_bf16(af[mf], bfr[nf], acc[mf][nf], 0, 0, 0);
    __syncthreads();
  }
  if (EPI == 1) {
    #pragma unroll
    for (int mf = 0; mf < 4; ++mf)
      #pragma unroll
      for (int nf = 0; nf < 4; ++nf)
        #pragma unroll
        for (int i = 0; i < 4; ++i) {
          int gm = rowA0 + wr * 64 + mf * 16 + ((lane >> 4) << 2) + i;
          int gn = rowB0 + wc * 64 + nf * 16 + (lane & 15);
          Cout[(size_t)gm * N + gn] = acc[mf][nf][i];
        }
  } else {
    short* dst = (bn < 16) ? qp : (bn < 32) ? kp : vp;
    int h = bn & 15;
    #pragma unroll
    for (int mf = 0; mf < 4; ++mf)
      #pragma unroll
      for (int nf = 0; nf < 4; ++nf)
        #pragma unroll
        for (int i = 0; i < 4; ++i) {
          int gm = rowA0 + wr * 64 + mf * 16 + ((lane >> 4) << 2) + i;
          int b = gm >> 11, t = gm & 2047;
          int d = wc * 64 + nf * 16 + (lane & 15);
          dst[(((size_t)b * NH + h) * TSEQ + t) * HD + d] = f2bf(acc[mf][nf][i]);
        }
  }
}

// ---------------- flash attention (causal), QBLK=128 (8 waves), KVBLK=64 ----------------
// Same verified per-wave math/swizzles as round-5; 8 waves amortize K/V staging
// over 2x the q-rows.  LDS swizzles (bijective chunk-XOR, rule #21 both-sides):
//  Ks : phys(row,k)  = row*128 + ((k>>3 ^ (row&7))<<3) + (k&7)   [pre-swizzled g2lds src]
//  Vt : phys(d,kv)   = d*64 + ((kv>>3 ^ (d&7) ^ ((d>>3)&7))<<3) + (kv&7)
//  Pl : phys(q,kv)   = q*64 + ((kv>>3 ^ (q&7))<<3) + (kv&7)
__global__ __launch_bounds__(512)
void flash_attn(const short* __restrict__ Q, const short* __restrict__ K,
                const short* __restrict__ V, short* __restrict__ Oout) {
  __shared__ short Ks[64 * 128];     // 16KB
  __shared__ short Vt[128 * 64];     // 16KB transposed V, swizzled
  __shared__ short Pl[8 * 16 * 64];  // 16KB per-wave P, swizzled
  int tid = threadIdx.x, lane = tid & 63, wave = tid >> 6;
  // heavy-first dispatch: qt descending across bid; same (b,h) sticks to one XCD
  int bid = blockIdx.x;
  int qt = (TSEQ / 128 - 1) - (bid >> 5);   // 0..15, heavy first
  int hb = bid & 31;
  int h = hb & 15, b = hb >> 4;
  size_t bh_off = ((size_t)b * NH + h) * TSEQ * HD;
  const short* Qp = Q + bh_off;
  const short* Kp = K + bh_off;
  const short* Vp = V + bh_off;
  int q0 = qt * 128 + wave * 16;
  short8 qf[4];
  #pragma unroll
  for (int ks = 0; ks < 4; ++ks)
    qf[ks] = *(const short8*)(Qp + (size_t)(q0 + (lane & 15)) * HD + ks * 32 + 8 * (lane >> 4));
  float m_run[4], l_run[4];
  f32x4 acc_o[8] = {};
  #pragma unroll
  for (int i = 0; i < 4; ++i) { m_run[i] = -INFINITY; l_run[i] = 0.f; }
  const float scale = 0.08838834764831845f;  // 1/sqrt(128)
  const int nTiles = 2 * qt + 2;             // kv up to (qt+1)*128
  for (int it = 0; it < nTiles; ++it) {
    int kv0 = it * 64;
    // V tile -> regs (issue first; latency hides under K staging)
    short8 vv[2];
    #pragma unroll
    for (int j = 0; j < 2; ++j) {
      int e = tid + j * 512;
      int r = e >> 4, c0 = (e & 15) * 8;
      vv[j] = *(const short8*)(Vp + (size_t)(kv0 + r) * HD + c0);
    }
    // stage K (64x128), pre-swizzled source chunk so swizzled read is linear-dest-safe
    #pragma unroll
    for (int j = 0; j < 2; ++j) {
      int c = tid + j * 512;          // physical 16B chunk index 0..1023
      int r = c >> 4, cc = c & 15;
      g2lds16(Kp + (size_t)(kv0 + r) * HD + ((cc ^ (r & 7)) << 3), Ks + c * 8);
    }
    // scatter V transpose into swizzled Vt
    #pragma unroll
    for (int j = 0; j < 2; ++j) {
      int e = tid + j * 512;
      int r = e >> 4, c0 = (e & 15) * 8;
      int rc = r >> 3, rl = r & 7;
      #pragma unroll
      for (int jj = 0; jj < 8; ++jj) {
        int d = c0 + jj;
        int pch = rc ^ (d & 7) ^ ((d >> 3) & 7);
        Vt[d * 64 + (pch << 3) + rl] = vv[j][jj];
      }
    }
    __syncthreads();
    // S = Q K^T  (16 q-rows per wave x 64 kv)
    f32x4 sa[4] = {};
    __builtin_amdgcn_s_setprio(1);
    #pragma unroll
    for (int nf = 0; nf < 4; ++nf)
      #pragma unroll
      for (int ks = 0; ks < 4; ++ks) {
        int row = nf * 16 + (lane & 15);
        int lch = ks * 4 + (lane >> 4);
        short8 kf = *(const short8*)(Ks + row * 128 + ((lch ^ (row & 7)) << 3));
        sa[nf] = __builtin_amdgcn_mfma_f32_16x16x32_bf16(qf[ks], kf, sa[nf], 0, 0, 0);
      }
    __builtin_amdgcn_s_setprio(0);
    bool maskTile = (it >= 2 * qt);   // last two tiles clip against the diagonal
    #pragma unroll
    for (int nf = 0; nf < 4; ++nf)
      #pragma unroll
      for (int i = 0; i < 4; ++i) {
        float s = sa[nf][i] * scale;
        if (maskTile) {
          int kvc = kv0 + nf * 16 + (lane & 15);
          int qr = q0 + ((lane >> 4) << 2) + i;
          if (kvc > qr) s = -INFINITY;
        }
        sa[nf][i] = s;
      }
    // online softmax per q-row (rows live across 16 lanes)
    #pragma unroll
    for (int i = 0; i < 4; ++i) {
      float t = fmaxf(fmaxf(sa[0][i], sa[1][i]), fmaxf(sa[2][i], sa[3][i]));
      t = fmaxf(t, __shfl_xor(t, 1));
      t = fmaxf(t, __shfl_xor(t, 2));
      t = fmaxf(t, __shfl_xor(t, 4));
      t = fmaxf(t, __shfl_xor(t, 8));
      float mn = fmaxf(m_run[i], t);
      float al = __expf(m_run[i] - mn);
      m_run[i] = mn;
      float su = 0.f;
      #pragma unroll
      for (int nf = 0; nf < 4; ++nf) {
        float p = __expf(sa[nf][i] - mn);
        sa[nf][i] = p;
        su += p;
      }
      su += __shfl_xor(su, 1);
      su += __shfl_xor(su, 2);
      su += __shfl_xor(su, 4);
      su += __shfl_xor(su, 8);
      l_run[i] = l_run[i] * al + su;
      #pragma unroll
      for (int nfd = 0; nfd < 8; ++nfd) acc_o[nfd][i] *= al;
    }
    // P -> LDS (per wave, swizzled)
    short* Pw = Pl + wave * 16 * 64;
    #pragma unroll
    for (int nf = 0; nf < 4; ++nf)
      #pragma unroll
      for (int i = 0; i < 4; ++i) {
        int qq = ((lane >> 4) << 2) + i;
        int kv = nf * 16 + (lane & 15);
        Pw[qq * 64 + (((kv >> 3) ^ (qq & 7)) << 3) + (kv & 7)] = f2bf(sa[nf][i]);
      }
    // O += P V
    __builtin_amdgcn_s_setprio(1);
    #pragma unroll
    for (int ks2 = 0; ks2 < 2; ++ks2) {
      int qq = lane & 15;
      int lchp = ks2 * 4 + (lane >> 4);
      short8 pf = *(const short8*)(Pw + qq * 64 + ((lchp ^ (qq & 7)) << 3));
      #pragma unroll
      for (int nfd = 0; nfd < 8; ++nfd) {
        int d = nfd * 16 + (lane & 15);
        int lch = ks2 * 4 + (lane >> 4);
        int pch = lch ^ (d & 7) ^ ((d >> 3) & 7);
        short8 vf = *(const short8*)(Vt + d * 64 + (pch << 3));
        acc_o[nfd] = __builtin_amdgcn_mfma_f32_16x16x32_bf16(pf, vf, acc_o[nfd], 0, 0, 0);
      }
    }
    __builtin_amdgcn_s_setprio(0);
    __syncthreads();
  }
  // epilogue: O /= l, write bf16 to attn_out [B,T,DIM]
  #pragma unroll
  for (int nfd = 0; nfd < 8; ++nfd)
    #pragma unroll
    for (int i = 0; i < 4; ++i) {
      int qr = q0 + ((lane >> 4) << 2) + i;
      int col = h * HD + nfd * 16 + (lane & 15);
      Oout[((size_t)b * TSEQ + qr) * DIMC + col] = f2bf(acc_o[nfd][i] / l_run[i]);
    }
}

extern "C" void kernel_launch(void* const* d_in, const int* in_sizes, int n_in,
                              void* d_out, int out_size, void* d_ws, size_t ws_size,
                              hipStream_t stream) {
  const float* x     = (const float*)d_in[0];
  const float* w_qkv = (const float*)d_in[1];
  const float* w_out = (const float*)d_in[2];
  float* out = (float*)d_out;
  char* ws = (char*)d_ws;
  size_t off = 0;
  auto alloc = [&](size_t bytes) {
    void* p = ws + off;
    off += (bytes + 255) & ~(size_t)255;
    return p;
  };
  float* cos_t = (float*)alloc((size_t)TSEQ * 64 * 4);
  float* sin_t = (float*)alloc((size_t)TSEQ * 64 * 4);
  short* xb    = (short*)alloc((size_t)MROWS * DIMC * 2);
  short* wqkvb = (short*)alloc((size_t)NQKV * DIMC * 2);
  short* woutb = (short*)alloc((size_t)DIMC * DIMC * 2);
  short* q     = (short*)alloc((size_t)BBATCH * NH * TSEQ * HD * 2);
  short* k     = (short*)alloc((size_t)BBATCH * NH * TSEQ * HD * 2);
  short* v     = (short*)alloc((size_t)BBATCH * NH * TSEQ * HD * 2);
  short* attn  = (short*)alloc((size_t)MROWS * DIMC * 2);

  rope_tables<<<(TSEQ * 64) / 256, 256, 0, stream>>>(cos_t, sin_t);
  cast_f32_bf16<<<(MROWS * DIMC / 8 + 255) / 256, 256, 0, stream>>>(x, xb, MROWS * DIMC / 8);
  cast_f32_bf16<<<(NQKV * DIMC / 8 + 255) / 256, 256, 0, stream>>>(w_qkv, wqkvb, NQKV * DIMC / 8);
  cast_f32_bf16<<<(DIMC * DIMC / 8 + 255) / 256, 256, 0, stream>>>(w_out, woutb, DIMC * DIMC / 8);

  gemm_bt<0><<<dim3(NQKV / 128, MROWS / 128), 256, 0, stream>>>(
      xb, wqkvb, MROWS, NQKV, DIMC, nullptr, q, k, v);

  rope_apply<<<(BBATCH * NH * TSEQ * 64) / 256, 256, 0, stream>>>(q, k, cos_t, sin_t);

  flash_attn<<<dim3((TSEQ / 128) * NH * BBATCH), 512, 0, stream>>>(q, k, v, attn);

  gemm_bt<1><<<dim3(DIMC / 128, MROWS / 128), 256, 0, stream>>>(
      attn, woutb, MROWS, DIMC, DIMC, out, nullptr, nullptr, nullptr);
}